// Round 10
// baseline (271.325 us; speedup 1.0000x reference)
//
#include <hip/hip_runtime.h>

#define CIN_B 512
#define CIN_F0 40
#define CIN_D 32
#define CIN_S 200

typedef _Float16 f16x8 __attribute__((ext_vector_type(8)));
typedef _Float16 f16x2 __attribute__((ext_vector_type(2)));
typedef float floatx16 __attribute__((ext_vector_type(16)));

__device__ __forceinline__ unsigned short f2h(float f) {
    _Float16 h = (_Float16)f;           // RNE
    return *(unsigned short*)&h;
}
__device__ __forceinline__ float h2f(unsigned short u) {
    return (float)(*(_Float16*)&u);
}
// v * broadcast(s2): 4 v_pk_mul_f16 sharing one scale register
__device__ __forceinline__ f16x8 mulbc(f16x8 v, unsigned int s2) {
    union { unsigned int u; f16x2 p; } sc; sc.u = s2;
    union { f16x8 h; f16x2 p[4]; } a, r;
    a.h = v;
#pragma unroll
    for (int q = 0; q < 4; ++q) r.p[q] = a.p[q] * sc.p;
    return r.h;
}

// R10: ALL prep work in ONE dispatch (launch-overhead reduction; the 4 prep
// kernels + out-zeroing are independent 256-thread kernels -> block-range
// dispatch). Ranges:
//   [0,120)      Wtk1[kc][nn][kw] = f16(W0[(i*40 + kk*16+kw)*200 + nn]), kc=i*3+kk
//   [120,640)    Wtk2 from W1 (kc=i*13+kk, kk==6 stored 0.5x; read by both
//                jh-halves of layer 2: 0.5x+0.5x == x, exact in fp16)
//   [640,2432)   W2t[n(224)][k(8192)] = f16(W2[k][n]) transpose, zero-padded
//   [2432,4992)  X0hd[b][d][i(48)] / Xh[b][i][d] = f16(X), pads zeroed
//   [4992,5792)  zero out[:,200:600] (atomic targets for L2 / l3 epilogues)
__global__ __launch_bounds__(256) void prep_all(
    const float* __restrict__ X,  const float* __restrict__ W0,
    const float* __restrict__ W1, const float* __restrict__ W2,
    unsigned short* __restrict__ Wtk1, unsigned short* __restrict__ Wtk2,
    unsigned short* __restrict__ W2t,  unsigned short* __restrict__ X0hd,
    unsigned short* __restrict__ Xh,   float* __restrict__ out) {
    __shared__ unsigned short T[32][33];
    const int bid = blockIdx.x;

    if (bid < 120) {                         // ---- prep_w (W0 -> Wtk1)
        const int kc = bid, nn = threadIdx.x;
        const int i = kc / 3, kk = kc - i * 3;
        unsigned short v[16];
#pragma unroll
        for (int kw = 0; kw < 16; ++kw) {
            int j = kk * 16 + kw;
            float f = 0.f;
            if (j < CIN_F0 && nn < CIN_S) f = W0[(size_t)(i * CIN_F0 + j) * CIN_S + nn];
            v[kw] = f2h(f);
        }
        uint4* dst = (uint4*)(Wtk1 + ((size_t)kc * 256 + nn) * 16);
        dst[0] = ((const uint4*)v)[0];
        dst[1] = ((const uint4*)v)[1];
    } else if (bid < 640) {                  // ---- prep_w2 (W1 -> Wtk2)
        const int kc = bid - 120, nn = threadIdx.x;
        const int i = kc / 13, kk = kc - i * 13;
        const float sc = (kk == 6) ? 0.5f : 1.0f;
        unsigned short v[16];
#pragma unroll
        for (int kw = 0; kw < 16; ++kw) {
            int j = kk * 16 + kw;
            float f = 0.f;
            if (j < CIN_S && nn < CIN_S) f = sc * W1[(size_t)(i * CIN_S + j) * CIN_S + nn];
            v[kw] = f2h(f);
        }
        uint4* dst = (uint4*)(Wtk2 + ((size_t)kc * 256 + nn) * 16);
        dst[0] = ((const uint4*)v)[0];
        dst[1] = ((const uint4*)v)[1];
    } else if (bid < 2432) {                 // ---- prep_w2t (W2 -> W2t)
        const int q0 = bid - 640;
        const int kt = q0 & 255, nt = q0 >> 8;      // 256 x 7
        const int tx = threadIdx.x & 31, ty = threadIdx.x >> 5;
#pragma unroll
        for (int q = 0; q < 4; ++q) {
            int kl = ty + 8 * q;
            int k = kt * 32 + kl, n = nt * 32 + tx;
            float f = (k < 8000 && n < CIN_S) ? W2[(size_t)k * CIN_S + n] : 0.f;
            T[kl][tx] = f2h(f);
        }
        __syncthreads();
#pragma unroll
        for (int q = 0; q < 4; ++q) {
            int nl = ty + 8 * q;
            W2t[(size_t)(nt * 32 + nl) * 8192 + kt * 32 + tx] = T[tx][nl];
        }
    } else if (bid < 4992) {                 // ---- prep_x
        int e = (bid - 2432) * 256 + threadIdx.x;   // 512*40*32
        int d = e & 31;
        int rest = e >> 5;
        int i = rest % CIN_F0;
        int b = rest / CIN_F0;
        unsigned short v = f2h(X[e]);
        Xh[e] = v;
        X0hd[((size_t)b * CIN_D + d) * 48 + i] = v;
        if (e < CIN_B * CIN_D * 8) {     // zero pads i=40..47
            int q = e & 7, dd = (e >> 3) & 31, bb = e >> 8;
            X0hd[((size_t)bb * CIN_D + dd) * 48 + 40 + q] = 0;
        }
    } else {                                 // ---- zero out[:,200:600]
        int g = (bid - 4992) * 256 + threadIdx.x;   // < 512*400
        int b = g / 400, t = g - b * 400;
        out[(size_t)b * 600 + 200 + t] = 0.f;
    }
}

// One layer. Block = NB batches x 7 waves (448 thr).
// Governing law (R0/R1/R5/R6/R8 fit): per-wave-step cost ~100 cyc, invariant
// to occupancy and prefetch structure -> MINIMIZE WAVE-STEPS: NB=2
// (4 MFMA/step). Main loop is the R0-proven plateau structure, UNTOUCHED.
// R10 change: MODE 2 d-sum epilogue atomicAdds the jh-partial straight into
// out[b,200+n] (2 adds/location; out[:,200:600] zeroed by prep_all) --
// removes the outp2 partial buffer and (with l3's atomics) the cin_outc pass.
// mfma_f32_32x32x16_f16: A[m=lane&31][k=(lane>>5)*8+e]; B[k][col=lane&31];
// C/D col=lane&31, row=(reg&3)+8*(reg>>2)+4*(lane>>5).
template <int NKC, int KCPI_TOT, int JROW, int MODE, int NB, int WPS>
__global__ __launch_bounds__(448, WPS)
void cin_layer(const unsigned short* __restrict__ Hsrc,
               const unsigned short* __restrict__ Xh,
               const unsigned short* __restrict__ Wtk,
               unsigned short* __restrict__ Hout,
               float* __restrict__ outp) {
    __shared__ __align__(16) unsigned short Bp[NB * NKC * 512];
    __shared__ unsigned int Xl[CIN_F0 * CIN_D];

    const int tid = threadIdx.x;
    const int b0 = blockIdx.x * NB;
    const int jh = (MODE == 1) ? 0 : blockIdx.y;
    const int kks = jh * 6;

    // stage packed x-pairs: Xl[i*32+d] = x[b0][i][d] | x[b0+1][i][d]<<16
    for (int e = tid; e < CIN_F0 * CIN_D; e += 448) {
        unsigned int lo = Xh[(size_t)b0 * (CIN_F0 * CIN_D) + e];
        unsigned int hi = (NB == 2) ? (unsigned int)Xh[(size_t)(b0 + 1) * (CIN_F0 * CIN_D) + e] : 0u;
        Xl[e] = lo | (hi << 16);
    }
    // stage B-frags into LDS (fragment order, i-invariant) — R10/R13 layout
    {
        const int j0 = (MODE == 1) ? 0 : jh * 96;
        uint4* Bpu = (uint4*)Bp;
        for (int g = tid; g < NB * 64 * NKC; g += 448) {
            int bb = g / (64 * NKC), r = g - bb * (64 * NKC);
            int d = r / (2 * NKC), c = r - d * (2 * NKC);
            uint4 v = ((const uint4*)Hsrc)[(((size_t)(b0 + bb) * CIN_D + d) * JROW + j0) / 8 + c];
            Bpu[(bb * NKC + (c >> 1)) * 64 + (c & 1) * 32 + d] = v;
        }
    }
    __syncthreads();

    const int wave = tid >> 6, lane = tid & 63;
    const int l32 = lane & 31, hl = lane >> 5;
    const int tile = wave;

    const int aB = (tile * 32 + l32) * 16 + hl * 8;   // per-lane element offset
    constexpr int NS = 20 * NKC;

    f16x8 Ar[2][2];   // [slot][0: i=iA, 1: i=iA+1]
    f16x8 Br[2][NB];  // [slot][b-index]

    auto ldA = [&](int s, int slot) {
        int ss = (s < NS) ? s : (NS - 1);
        int iA = 2 * (ss / NKC), kk = ss % NKC;
        int e = (iA * KCPI_TOT + kks + kk) * 4096 + aB;
        Ar[slot][0] = *(const f16x8*)(Wtk + e);
        Ar[slot][1] = *(const f16x8*)(Wtk + e + KCPI_TOT * 4096);
    };
    auto ldB = [&](int s, int slot) {
        int ss = (s < NS) ? s : (NS - 1);
        int kk = ss % NKC;
        Br[slot][0] = *(const f16x8*)&Bp[(0 * NKC + kk) * 512 + lane * 8];
        if constexpr (NB == 2)
            Br[slot][1] = *(const f16x8*)&Bp[(1 * NKC + kk) * 512 + lane * 8];
    };

    ldA(0, 0);
    ldA(1, 1);
    ldB(0, 0);

    floatx16 acc0, acc1;
#pragma unroll
    for (int r = 0; r < 16; ++r) acc0[r] = 0.f;
    if constexpr (NB == 2) {
#pragma unroll
        for (int r = 0; r < 16; ++r) acc1[r] = 0.f;
    }
    unsigned int xs0a = 0, xs1a = 0, xs0b = 0, xs1b = 0;

#pragma unroll 1
    for (int s0 = 0; s0 < NS; s0 += 2 * NKC) {
#pragma unroll
        for (int t = 0; t < 2 * NKC; ++t) {
            const int s = s0 + t;
            const int kk = t % NKC;                   // literal
            if (kk == 0) {                            // xs update (2x per body)
                const int iA = (s0 / NKC + (t ? 1 : 0)) * 2;
                unsigned int xpa = Xl[iA * CIN_D + l32];
                unsigned int xpb = Xl[(iA + 1) * CIN_D + l32];
                xs0a = (xpa & 0xffffu) | (xpa << 16);
                xs0b = (xpb & 0xffffu) | (xpb << 16);
                if constexpr (NB == 2) {
                    xs1a = (xpa >> 16) | (xpa & 0xffff0000u);
                    xs1b = (xpb >> 16) | (xpb & 0xffff0000u);
                }
            }
            ldB(s + 1, (t + 1) & 1);                  // B prefetch, 1 ahead
            const int sl = t & 1;
            acc0 = __builtin_amdgcn_mfma_f32_32x32x16_f16(
                Ar[sl][0], mulbc(Br[sl][0], xs0a), acc0, 0, 0, 0);
            if constexpr (NB == 2)
                acc1 = __builtin_amdgcn_mfma_f32_32x32x16_f16(
                    Ar[sl][0], mulbc(Br[sl][1], xs1a), acc1, 0, 0, 0);
            acc0 = __builtin_amdgcn_mfma_f32_32x32x16_f16(
                Ar[sl][1], mulbc(Br[sl][0], xs0b), acc0, 0, 0, 0);
            if constexpr (NB == 2)
                acc1 = __builtin_amdgcn_mfma_f32_32x32x16_f16(
                    Ar[sl][1], mulbc(Br[sl][1], xs1b), acc1, 0, 0, 0);
            ldA(s + 2, sl);                           // A prefetch, 2 ahead
        }
    }

    // ---- epilogue ----
#pragma unroll
    for (int bb = 0; bb < NB; ++bb) {
        const floatx16& a = bb ? acc1 : acc0;

        if constexpr (MODE == 1) {   // H1[b][d][n] f16, n-tile of 32
            unsigned short* dst =
                Hout + ((size_t)(b0 + bb) * CIN_D + l32) * 224 + tile * 32;
#pragma unroll
            for (int qd = 0; qd < 4; ++qd) {
                ushort4 pk;
                pk.x = f2h(a[4 * qd + 0]);
                pk.y = f2h(a[4 * qd + 1]);
                pk.z = f2h(a[4 * qd + 2]);
                pk.w = f2h(a[4 * qd + 3]);
                *(ushort4*)&dst[8 * qd + 4 * hl] = pk;
            }
        }
        if constexpr (MODE == 2) {   // Hacc[jh][b][n][d] f16 partials
            unsigned short* hb2 =
                Hout + (((size_t)jh * CIN_B + b0 + bb) * 208) * CIN_D + l32;
#pragma unroll
            for (int r = 0; r < 16; ++r) {
                int n = tile * 32 + (r & 3) + 8 * (r >> 2) + 4 * hl;
                if (n < 208) hb2[(size_t)n * CIN_D] = f2h(a[r]);
            }
        }

        // d-sum over col = l32 (fp32)
#pragma unroll
        for (int r = 0; r < 16; ++r) {
            float v = a[r];
            v += __shfl_xor(v, 1);
            v += __shfl_xor(v, 2);
            v += __shfl_xor(v, 4);
            v += __shfl_xor(v, 8);
            v += __shfl_xor(v, 16);
            if (l32 == 0) {
                int n = tile * 32 + (r & 3) + 8 * (r >> 2) + 4 * hl;
                if (n < CIN_S) {
                    if constexpr (MODE == 1)
                        outp[(size_t)(b0 + bb) * 600 + n] = v;           // direct
                    else
                        atomicAdd(&outp[(size_t)(b0 + bb) * 600 + 200 + n], v);
                }
            }
        }
    }
}

// G[b][k=i*200+j (pad 8192)] = f16( sum_d x0[b,i,d] * h2[b,j,d] ), with the
// jh-partial combine FUSED: h2 = p0 + p1 read directly from Hacc (f16x8 add
// == f32-add-then-round, exact). 7 waves/block (one j-tile per wave).
// D[m=i][col=j]; A-frag = x0[i][d] (Xh, d-contig); B-frag = h2[j][d].
__global__ __launch_bounds__(448) void cin_g(const unsigned short* __restrict__ Xh,
                                             const unsigned short* __restrict__ Hacc,
                                             unsigned short* __restrict__ G) {
    const int b = blockIdx.x;
    const int wave = threadIdx.x >> 6, lane = threadIdx.x & 63;
    const int l32 = lane & 31, hl = lane >> 5;
    const int jt = wave;                 // j-tile 0..6

    // zero k-pad [8000,8192): 192 f16 = 24 lanes x 16 B (wave 0)
    if (wave == 0 && lane < 24) {
        uint4 z; z.x = z.y = z.z = z.w = 0;
        ((uint4*)(G + (size_t)b * 8192 + 8000))[lane] = z;
    }

    f16x8 zed;
#pragma unroll
    for (int q = 0; q < 8; ++q) zed[q] = (_Float16)0.f;

    f16x8 a[2][2];   // [i-tile][k-half]
#pragma unroll
    for (int it = 0; it < 2; ++it) {
        int i = it * 32 + l32;
#pragma unroll
        for (int kh = 0; kh < 2; ++kh)
            a[it][kh] = (i < CIN_F0)
                ? *(const f16x8*)&Xh[((size_t)b * CIN_F0 + i) * CIN_D + kh * 16 + hl * 8]
                : zed;
    }

    const int j = jt * 32 + l32;
    const unsigned short* p0 = Hacc + ((size_t)b * 208 + j) * CIN_D;
    const unsigned short* p1 = Hacc + ((size_t)(CIN_B + b) * 208 + j) * CIN_D;
    f16x8 bf[2];
#pragma unroll
    for (int kh = 0; kh < 2; ++kh)
        bf[kh] = (j < 208)
            ? (*(const f16x8*)(p0 + kh * 16 + hl * 8) +
               *(const f16x8*)(p1 + kh * 16 + hl * 8))
            : zed;

#pragma unroll
    for (int it = 0; it < 2; ++it) {
        floatx16 acc;
#pragma unroll
        for (int r = 0; r < 16; ++r) acc[r] = 0.f;
        acc = __builtin_amdgcn_mfma_f32_32x32x16_f16(a[it][0], bf[0], acc, 0, 0, 0);
        acc = __builtin_amdgcn_mfma_f32_32x32x16_f16(a[it][1], bf[1], acc, 0, 0, 0);
#pragma unroll
        for (int r = 0; r < 16; ++r) {
            int row = (r & 3) + 8 * (r >> 2) + 4 * hl;
            int i = it * 32 + row, jj = jt * 32 + l32;
            if (i < CIN_F0 && jj < CIN_S)
                G[(size_t)b * 8192 + i * CIN_S + jj] = f2h(acc[r]);
        }
    }
}

// out3 GEMM: C[n=200, b=512] = sum_k W2t[n][k] * G[b][k], k split in 16 chunks
// of 512 (32 k16-steps), 1792 one-wave blocks = 7 waves/CU (R8 win).
// R10: each block atomicAdds its tile into out[b,400+n] (16 adds/location;
// zeroed by prep_all) -- outp3 buffer and the cin_outc dispatch deleted.
// 2-deep register rotation; final prefetch over-reads <=64 B (mapped).
__global__ __launch_bounds__(64) void cin_l3(const unsigned short* __restrict__ W2t,
                                             const unsigned short* __restrict__ G,
                                             float* __restrict__ out) {
    const int mt = blockIdx.x;          // 0..6   n-tile
    const int bt = blockIdx.y;          // 0..15  b-tile
    const int kch = blockIdx.z;         // 0..15  k-chunk
    const int lane = threadIdx.x, l32 = lane & 31, hl = lane >> 5;

    const unsigned short* pa = W2t + (size_t)(mt * 32 + l32) * 8192 + kch * 512 + hl * 8;
    const unsigned short* pb = G   + (size_t)(bt * 32 + l32) * 8192 + kch * 512 + hl * 8;

    floatx16 acc;
#pragma unroll
    for (int r = 0; r < 16; ++r) acc[r] = 0.f;

    f16x8 Aa[2], Bb[2];
    Aa[0] = *(const f16x8*)(pa);       Bb[0] = *(const f16x8*)(pb);
    Aa[1] = *(const f16x8*)(pa + 16);  Bb[1] = *(const f16x8*)(pb + 16);

#pragma unroll 1
    for (int s0 = 0; s0 < 32; s0 += 2) {
#pragma unroll
        for (int t = 0; t < 2; ++t) {
            acc = __builtin_amdgcn_mfma_f32_32x32x16_f16(Aa[t], Bb[t], acc, 0, 0, 0);
            Aa[t] = *(const f16x8*)(pa + (s0 + t + 2) * 16);
            Bb[t] = *(const f16x8*)(pb + (s0 + t + 2) * 16);
        }
    }

#pragma unroll
    for (int r = 0; r < 16; ++r) {
        int n = mt * 32 + (r & 3) + 8 * (r >> 2) + 4 * hl;
        if (n < CIN_S)
            atomicAdd(&out[(size_t)(bt * 32 + l32) * 600 + 400 + n], acc[r]);
    }
}

extern "C" void kernel_launch(void* const* d_in, const int* in_sizes, int n_in,
                              void* d_out, int out_size, void* d_ws, size_t ws_size,
                              hipStream_t stream) {
    const float* X  = (const float*)d_in[0];
    const float* W0 = (const float*)d_in[1];
    const float* W1 = (const float*)d_in[2];
    const float* W2 = (const float*)d_in[3];
    float* out = (float*)d_out;

    unsigned short* Wtk1 = (unsigned short*)d_ws;             // 120*4096
    unsigned short* Wtk2 = Wtk1 + (size_t)120 * 4096;         // 520*4096
    unsigned short* W2t  = Wtk2 + (size_t)520 * 4096;         // 224*8192
    unsigned short* X0hd = W2t + (size_t)224 * 8192;          // 512*32*48
    unsigned short* Xh   = X0hd + (size_t)CIN_B * CIN_D * 48; // 512*40*32
    unsigned short* H1   = Xh + (size_t)CIN_B * CIN_F0 * CIN_D; // 512*32*224
    unsigned short* G    = H1 + (size_t)CIN_B * CIN_D * 224;  // 512*8192
    unsigned short* Hacc = G + (size_t)CIN_B * 8192;          // 2*512*208*32
    // (G placed before Hacc so cin_l3's <=64 B tail over-read stays mapped)
    // total ws ~41 MB

    // 1 merged prep dispatch (was 4 + zeroing work): see prep_all ranges.
    prep_all<<<5792, 256, 0, stream>>>(X, W0, W1, W2, Wtk1, Wtk2, W2t, X0hd, Xh, out);

    // layer 1: NB=2, writes H1 + out[:,0:200] direct
    cin_layer<3, 3, 48, 1, 2, 4><<<dim3(CIN_B / 2, 1), 448, 0, stream>>>(
        X0hd, Xh, Wtk1, H1, out);
    // layer 2: NB=2 R0-proven structure; d-sum atomicAdds into out[:,200:400]
    cin_layer<7, 13, 224, 2, 2, 4><<<dim3(CIN_B / 2, 2), 448, 0, stream>>>(
        H1, Xh, Wtk2, Hacc, out);

    // fused combine + G outer-product
    cin_g<<<CIN_B, 448, 0, stream>>>(Xh, Hacc, G);
    // layer-3 GEMM, atomicAdd into out[:,400:600]
    cin_l3<<<dim3(7, 16, 16), 64, 0, stream>>>(W2t, G, out);
}

// Round 11
// 207.977 us; speedup vs baseline: 1.3046x; 1.3046x over previous
//
#include <hip/hip_runtime.h>

#define CIN_B 512
#define CIN_F0 40
#define CIN_D 32
#define CIN_S 200

typedef _Float16 f16x8 __attribute__((ext_vector_type(8)));
typedef _Float16 f16x2 __attribute__((ext_vector_type(2)));
typedef float floatx16 __attribute__((ext_vector_type(16)));

__device__ __forceinline__ unsigned short f2h(float f) {
    _Float16 h = (_Float16)f;           // RNE
    return *(unsigned short*)&h;
}
__device__ __forceinline__ float h2f(unsigned short u) {
    return (float)(*(_Float16*)&u);
}
// v * broadcast(s2): 4 v_pk_mul_f16 sharing one scale register
__device__ __forceinline__ f16x8 mulbc(f16x8 v, unsigned int s2) {
    union { unsigned int u; f16x2 p; } sc; sc.u = s2;
    union { f16x8 h; f16x2 p[4]; } a, r;
    a.h = v;
#pragma unroll
    for (int q = 0; q < 4; ++q) r.p[q] = a.p[q] * sc.p;
    return r.h;
}

// R11: the 4 prep kernels merged into ONE dispatch (launch-overhead cut; the
// safe half of R10). NO atomic-output branch: R10's counters showed scattered
// fp32 atomicAdds cost ~9x coalesced stores (layer-2 WRITE_SIZE +2.4MB,
// +3us from 205K atomics; l3's 1.8M atomics ~+30us) -- partial buffers +
// cin_outc restored, bit-identical to R9's 220.2us build. Ranges:
//   [0,120)      Wtk1[kc][nn][kw] = f16(W0[(i*40 + kk*16+kw)*200 + nn]), kc=i*3+kk
//   [120,640)    Wtk2 from W1 (kc=i*13+kk, kk==6 stored 0.5x; read by both
//                jh-halves of layer 2: 0.5x+0.5x == x, exact in fp16)
//   [640,2432)   W2t[n(224)][k(8192)] = f16(W2[k][n]) transpose, zero-padded
//   [2432,4992)  X0hd[b][d][i(48)] / Xh[b][i][d] = f16(X), pads zeroed
__global__ __launch_bounds__(256) void prep_all(
    const float* __restrict__ X,  const float* __restrict__ W0,
    const float* __restrict__ W1, const float* __restrict__ W2,
    unsigned short* __restrict__ Wtk1, unsigned short* __restrict__ Wtk2,
    unsigned short* __restrict__ W2t,  unsigned short* __restrict__ X0hd,
    unsigned short* __restrict__ Xh) {
    __shared__ unsigned short T[32][33];
    const int bid = blockIdx.x;

    if (bid < 120) {                         // ---- prep_w (W0 -> Wtk1)
        const int kc = bid, nn = threadIdx.x;
        const int i = kc / 3, kk = kc - i * 3;
        unsigned short v[16];
#pragma unroll
        for (int kw = 0; kw < 16; ++kw) {
            int j = kk * 16 + kw;
            float f = 0.f;
            if (j < CIN_F0 && nn < CIN_S) f = W0[(size_t)(i * CIN_F0 + j) * CIN_S + nn];
            v[kw] = f2h(f);
        }
        uint4* dst = (uint4*)(Wtk1 + ((size_t)kc * 256 + nn) * 16);
        dst[0] = ((const uint4*)v)[0];
        dst[1] = ((const uint4*)v)[1];
    } else if (bid < 640) {                  // ---- prep_w2 (W1 -> Wtk2)
        const int kc = bid - 120, nn = threadIdx.x;
        const int i = kc / 13, kk = kc - i * 13;
        const float sc = (kk == 6) ? 0.5f : 1.0f;
        unsigned short v[16];
#pragma unroll
        for (int kw = 0; kw < 16; ++kw) {
            int j = kk * 16 + kw;
            float f = 0.f;
            if (j < CIN_S && nn < CIN_S) f = sc * W1[(size_t)(i * CIN_S + j) * CIN_S + nn];
            v[kw] = f2h(f);
        }
        uint4* dst = (uint4*)(Wtk2 + ((size_t)kc * 256 + nn) * 16);
        dst[0] = ((const uint4*)v)[0];
        dst[1] = ((const uint4*)v)[1];
    } else if (bid < 2432) {                 // ---- prep_w2t (W2 -> W2t)
        const int q0 = bid - 640;
        const int kt = q0 & 255, nt = q0 >> 8;      // 256 x 7
        const int tx = threadIdx.x & 31, ty = threadIdx.x >> 5;
#pragma unroll
        for (int q = 0; q < 4; ++q) {
            int kl = ty + 8 * q;
            int k = kt * 32 + kl, n = nt * 32 + tx;
            float f = (k < 8000 && n < CIN_S) ? W2[(size_t)k * CIN_S + n] : 0.f;
            T[kl][tx] = f2h(f);
        }
        __syncthreads();
#pragma unroll
        for (int q = 0; q < 4; ++q) {
            int nl = ty + 8 * q;
            W2t[(size_t)(nt * 32 + nl) * 8192 + kt * 32 + tx] = T[tx][nl];
        }
    } else {                                 // ---- prep_x
        int e = (bid - 2432) * 256 + threadIdx.x;   // 512*40*32
        int d = e & 31;
        int rest = e >> 5;
        int i = rest % CIN_F0;
        int b = rest / CIN_F0;
        unsigned short v = f2h(X[e]);
        Xh[e] = v;
        X0hd[((size_t)b * CIN_D + d) * 48 + i] = v;
        if (e < CIN_B * CIN_D * 8) {     // zero pads i=40..47
            int q = e & 7, dd = (e >> 3) & 31, bb = e >> 8;
            X0hd[((size_t)bb * CIN_D + dd) * 48 + 40 + q] = 0;
        }
    }
}

// One layer. Block = NB batches x 7 waves (448 thr).
// Governing law (R0/R1/R5/R6/R8 fit): per-wave-step cost ~100 cyc, invariant
// to occupancy and prefetch structure -> MINIMIZE WAVE-STEPS: NB=2
// (4 MFMA/step). Main loop is the R0-proven plateau structure, UNTOUCHED.
// Coalesced partial-buffer epilogues (R9-exact; R10's atomics regressed).
// mfma_f32_32x32x16_f16: A[m=lane&31][k=(lane>>5)*8+e]; B[k][col=lane&31];
// C/D col=lane&31, row=(reg&3)+8*(reg>>2)+4*(lane>>5).
template <int NKC, int KCPI_TOT, int JROW, int MODE, int NB, int WPS>
__global__ __launch_bounds__(448, WPS)
void cin_layer(const unsigned short* __restrict__ Hsrc,
               const unsigned short* __restrict__ Xh,
               const unsigned short* __restrict__ Wtk,
               unsigned short* __restrict__ Hout,
               float* __restrict__ outp) {
    __shared__ __align__(16) unsigned short Bp[NB * NKC * 512];
    __shared__ unsigned int Xl[CIN_F0 * CIN_D];

    const int tid = threadIdx.x;
    const int b0 = blockIdx.x * NB;
    const int jh = (MODE == 1) ? 0 : blockIdx.y;
    const int kks = jh * 6;

    // stage packed x-pairs: Xl[i*32+d] = x[b0][i][d] | x[b0+1][i][d]<<16
    for (int e = tid; e < CIN_F0 * CIN_D; e += 448) {
        unsigned int lo = Xh[(size_t)b0 * (CIN_F0 * CIN_D) + e];
        unsigned int hi = (NB == 2) ? (unsigned int)Xh[(size_t)(b0 + 1) * (CIN_F0 * CIN_D) + e] : 0u;
        Xl[e] = lo | (hi << 16);
    }
    // stage B-frags into LDS (fragment order, i-invariant) — R10/R13 layout
    {
        const int j0 = (MODE == 1) ? 0 : jh * 96;
        uint4* Bpu = (uint4*)Bp;
        for (int g = tid; g < NB * 64 * NKC; g += 448) {
            int bb = g / (64 * NKC), r = g - bb * (64 * NKC);
            int d = r / (2 * NKC), c = r - d * (2 * NKC);
            uint4 v = ((const uint4*)Hsrc)[(((size_t)(b0 + bb) * CIN_D + d) * JROW + j0) / 8 + c];
            Bpu[(bb * NKC + (c >> 1)) * 64 + (c & 1) * 32 + d] = v;
        }
    }
    __syncthreads();

    const int wave = tid >> 6, lane = tid & 63;
    const int l32 = lane & 31, hl = lane >> 5;
    const int tile = wave;

    const int aB = (tile * 32 + l32) * 16 + hl * 8;   // per-lane element offset
    constexpr int NS = 20 * NKC;

    f16x8 Ar[2][2];   // [slot][0: i=iA, 1: i=iA+1]
    f16x8 Br[2][NB];  // [slot][b-index]

    auto ldA = [&](int s, int slot) {
        int ss = (s < NS) ? s : (NS - 1);
        int iA = 2 * (ss / NKC), kk = ss % NKC;
        int e = (iA * KCPI_TOT + kks + kk) * 4096 + aB;
        Ar[slot][0] = *(const f16x8*)(Wtk + e);
        Ar[slot][1] = *(const f16x8*)(Wtk + e + KCPI_TOT * 4096);
    };
    auto ldB = [&](int s, int slot) {
        int ss = (s < NS) ? s : (NS - 1);
        int kk = ss % NKC;
        Br[slot][0] = *(const f16x8*)&Bp[(0 * NKC + kk) * 512 + lane * 8];
        if constexpr (NB == 2)
            Br[slot][1] = *(const f16x8*)&Bp[(1 * NKC + kk) * 512 + lane * 8];
    };

    ldA(0, 0);
    ldA(1, 1);
    ldB(0, 0);

    floatx16 acc0, acc1;
#pragma unroll
    for (int r = 0; r < 16; ++r) acc0[r] = 0.f;
    if constexpr (NB == 2) {
#pragma unroll
        for (int r = 0; r < 16; ++r) acc1[r] = 0.f;
    }
    unsigned int xs0a = 0, xs1a = 0, xs0b = 0, xs1b = 0;

#pragma unroll 1
    for (int s0 = 0; s0 < NS; s0 += 2 * NKC) {
#pragma unroll
        for (int t = 0; t < 2 * NKC; ++t) {
            const int s = s0 + t;
            const int kk = t % NKC;                   // literal
            if (kk == 0) {                            // xs update (2x per body)
                const int iA = (s0 / NKC + (t ? 1 : 0)) * 2;
                unsigned int xpa = Xl[iA * CIN_D + l32];
                unsigned int xpb = Xl[(iA + 1) * CIN_D + l32];
                xs0a = (xpa & 0xffffu) | (xpa << 16);
                xs0b = (xpb & 0xffffu) | (xpb << 16);
                if constexpr (NB == 2) {
                    xs1a = (xpa >> 16) | (xpa & 0xffff0000u);
                    xs1b = (xpb >> 16) | (xpb & 0xffff0000u);
                }
            }
            ldB(s + 1, (t + 1) & 1);                  // B prefetch, 1 ahead
            const int sl = t & 1;
            acc0 = __builtin_amdgcn_mfma_f32_32x32x16_f16(
                Ar[sl][0], mulbc(Br[sl][0], xs0a), acc0, 0, 0, 0);
            if constexpr (NB == 2)
                acc1 = __builtin_amdgcn_mfma_f32_32x32x16_f16(
                    Ar[sl][0], mulbc(Br[sl][1], xs1a), acc1, 0, 0, 0);
            acc0 = __builtin_amdgcn_mfma_f32_32x32x16_f16(
                Ar[sl][1], mulbc(Br[sl][0], xs0b), acc0, 0, 0, 0);
            if constexpr (NB == 2)
                acc1 = __builtin_amdgcn_mfma_f32_32x32x16_f16(
                    Ar[sl][1], mulbc(Br[sl][1], xs1b), acc1, 0, 0, 0);
            ldA(s + 2, sl);                           // A prefetch, 2 ahead
        }
    }

    // ---- epilogue ----
#pragma unroll
    for (int bb = 0; bb < NB; ++bb) {
        const floatx16& a = bb ? acc1 : acc0;

        if constexpr (MODE == 1) {   // H1[b][d][n] f16, n-tile of 32
            unsigned short* dst =
                Hout + ((size_t)(b0 + bb) * CIN_D + l32) * 224 + tile * 32;
#pragma unroll
            for (int qd = 0; qd < 4; ++qd) {
                ushort4 pk;
                pk.x = f2h(a[4 * qd + 0]);
                pk.y = f2h(a[4 * qd + 1]);
                pk.z = f2h(a[4 * qd + 2]);
                pk.w = f2h(a[4 * qd + 3]);
                *(ushort4*)&dst[8 * qd + 4 * hl] = pk;
            }
        }
        if constexpr (MODE == 2) {   // Hacc[jh][b][n][d] f16 partials
            unsigned short* hb2 =
                Hout + (((size_t)jh * CIN_B + b0 + bb) * 208) * CIN_D + l32;
#pragma unroll
            for (int r = 0; r < 16; ++r) {
                int n = tile * 32 + (r & 3) + 8 * (r >> 2) + 4 * hl;
                if (n < 208) hb2[(size_t)n * CIN_D] = f2h(a[r]);
            }
        }

        // d-sum over col = l32 (fp32)
#pragma unroll
        for (int r = 0; r < 16; ++r) {
            float v = a[r];
            v += __shfl_xor(v, 1);
            v += __shfl_xor(v, 2);
            v += __shfl_xor(v, 4);
            v += __shfl_xor(v, 8);
            v += __shfl_xor(v, 16);
            if (l32 == 0) {
                int n = tile * 32 + (r & 3) + 8 * (r >> 2) + 4 * hl;
                if (n < CIN_S) {
                    if constexpr (MODE == 1)
                        outp[(size_t)(b0 + bb) * 600 + n] = v;   // direct to out
                    else
                        outp[((size_t)jh * CIN_B + b0 + bb) * CIN_S + n] = v;
                }
            }
        }
    }
}

// G[b][k=i*200+j (pad 8192)] = f16( sum_d x0[b,i,d] * h2[b,j,d] ), with the
// jh-partial combine FUSED: h2 = p0 + p1 read directly from Hacc (f16x8 add
// == f32-add-then-round, exact). 7 waves/block (one j-tile per wave).
// D[m=i][col=j]; A-frag = x0[i][d] (Xh, d-contig); B-frag = h2[j][d].
__global__ __launch_bounds__(448) void cin_g(const unsigned short* __restrict__ Xh,
                                             const unsigned short* __restrict__ Hacc,
                                             unsigned short* __restrict__ G) {
    const int b = blockIdx.x;
    const int wave = threadIdx.x >> 6, lane = threadIdx.x & 63;
    const int l32 = lane & 31, hl = lane >> 5;
    const int jt = wave;                 // j-tile 0..6

    // zero k-pad [8000,8192): 192 f16 = 24 lanes x 16 B (wave 0)
    if (wave == 0 && lane < 24) {
        uint4 z; z.x = z.y = z.z = z.w = 0;
        ((uint4*)(G + (size_t)b * 8192 + 8000))[lane] = z;
    }

    f16x8 zed;
#pragma unroll
    for (int q = 0; q < 8; ++q) zed[q] = (_Float16)0.f;

    f16x8 a[2][2];   // [i-tile][k-half]
#pragma unroll
    for (int it = 0; it < 2; ++it) {
        int i = it * 32 + l32;
#pragma unroll
        for (int kh = 0; kh < 2; ++kh)
            a[it][kh] = (i < CIN_F0)
                ? *(const f16x8*)&Xh[((size_t)b * CIN_F0 + i) * CIN_D + kh * 16 + hl * 8]
                : zed;
    }

    const int j = jt * 32 + l32;
    const unsigned short* p0 = Hacc + ((size_t)b * 208 + j) * CIN_D;
    const unsigned short* p1 = Hacc + ((size_t)(CIN_B + b) * 208 + j) * CIN_D;
    f16x8 bf[2];
#pragma unroll
    for (int kh = 0; kh < 2; ++kh)
        bf[kh] = (j < 208)
            ? (*(const f16x8*)(p0 + kh * 16 + hl * 8) +
               *(const f16x8*)(p1 + kh * 16 + hl * 8))
            : zed;

#pragma unroll
    for (int it = 0; it < 2; ++it) {
        floatx16 acc;
#pragma unroll
        for (int r = 0; r < 16; ++r) acc[r] = 0.f;
        acc = __builtin_amdgcn_mfma_f32_32x32x16_f16(a[it][0], bf[0], acc, 0, 0, 0);
        acc = __builtin_amdgcn_mfma_f32_32x32x16_f16(a[it][1], bf[1], acc, 0, 0, 0);
#pragma unroll
        for (int r = 0; r < 16; ++r) {
            int row = (r & 3) + 8 * (r >> 2) + 4 * hl;
            int i = it * 32 + row, jj = jt * 32 + l32;
            if (i < CIN_F0 && jj < CIN_S)
                G[(size_t)b * 8192 + i * CIN_S + jj] = f2h(acc[r]);
        }
    }
}

// out3 GEMM: C[n=200, b=512] = sum_k W2t[n][k] * G[b][k], k split in 16 chunks
// of 512 (32 k16-steps), 1792 one-wave blocks = 7 waves/CU (R8 win).
// Coalesced f32 partial stores (R9-exact; atomics regressed in R10).
// 2-deep register rotation; final prefetch over-reads <=64 B (mapped).
__global__ __launch_bounds__(64) void cin_l3(const unsigned short* __restrict__ W2t,
                                             const unsigned short* __restrict__ G,
                                             float* __restrict__ outp3) {
    const int mt = blockIdx.x;          // 0..6   n-tile
    const int bt = blockIdx.y;          // 0..15  b-tile
    const int kch = blockIdx.z;         // 0..15  k-chunk
    const int lane = threadIdx.x, l32 = lane & 31, hl = lane >> 5;

    const unsigned short* pa = W2t + (size_t)(mt * 32 + l32) * 8192 + kch * 512 + hl * 8;
    const unsigned short* pb = G   + (size_t)(bt * 32 + l32) * 8192 + kch * 512 + hl * 8;

    floatx16 acc;
#pragma unroll
    for (int r = 0; r < 16; ++r) acc[r] = 0.f;

    f16x8 Aa[2], Bb[2];
    Aa[0] = *(const f16x8*)(pa);       Bb[0] = *(const f16x8*)(pb);
    Aa[1] = *(const f16x8*)(pa + 16);  Bb[1] = *(const f16x8*)(pb + 16);

#pragma unroll 1
    for (int s0 = 0; s0 < 32; s0 += 2) {
#pragma unroll
        for (int t = 0; t < 2; ++t) {
            acc = __builtin_amdgcn_mfma_f32_32x32x16_f16(Aa[t], Bb[t], acc, 0, 0, 0);
            Aa[t] = *(const f16x8*)(pa + (s0 + t + 2) * 16);
            Bb[t] = *(const f16x8*)(pb + (s0 + t + 2) * 16);
        }
    }

#pragma unroll
    for (int r = 0; r < 16; ++r) {
        int n = mt * 32 + (r & 3) + 8 * (r >> 2) + 4 * hl;
        if (n < CIN_S)
            outp3[((size_t)kch * CIN_B + bt * 32 + l32) * CIN_S + n] = acc[r];
    }
}

// out[b, 200+t]: half 0 from 2 jh-partials (outp2), half 1 from 16 k-chunk
// partials (outp3).
__global__ __launch_bounds__(256) void cin_outc(const float* __restrict__ p2,
                                                const float* __restrict__ p3,
                                                float* __restrict__ out) {
    int e = blockIdx.x * 256 + threadIdx.x;   // 512*400 exact
    int b = e / 400, t = e - b * 400;
    int half = t / 200, n = t - half * 200;
    float s;
    if (half == 0) {
        s = p2[(size_t)b * CIN_S + n] + p2[(size_t)(CIN_B + b) * CIN_S + n];
    } else {
        s = 0.f;
#pragma unroll
        for (int q = 0; q < 16; ++q)
            s += p3[((size_t)q * CIN_B + b) * CIN_S + n];
    }
    out[(size_t)b * 600 + 200 + half * 200 + n] = s;
}

extern "C" void kernel_launch(void* const* d_in, const int* in_sizes, int n_in,
                              void* d_out, int out_size, void* d_ws, size_t ws_size,
                              hipStream_t stream) {
    const float* X  = (const float*)d_in[0];
    const float* W0 = (const float*)d_in[1];
    const float* W1 = (const float*)d_in[2];
    const float* W2 = (const float*)d_in[3];
    float* out = (float*)d_out;

    unsigned short* Wtk1 = (unsigned short*)d_ws;             // 120*4096
    unsigned short* Wtk2 = Wtk1 + (size_t)120 * 4096;         // 520*4096
    unsigned short* W2t  = Wtk2 + (size_t)520 * 4096;         // 224*8192
    unsigned short* X0hd = W2t + (size_t)224 * 8192;          // 512*32*48
    unsigned short* Xh   = X0hd + (size_t)CIN_B * CIN_D * 48; // 512*40*32
    unsigned short* H1   = Xh + (size_t)CIN_B * CIN_F0 * CIN_D; // 512*32*224
    unsigned short* Hacc = H1 + (size_t)CIN_B * CIN_D * 224;  // 2*512*208*32
    float* outp2 = (float*)(Hacc + (size_t)2 * CIN_B * 208 * CIN_D); // 2*512*200
    float* outp3 = outp2 + (size_t)2 * CIN_B * CIN_S;              // 16*512*200
    unsigned short* G = (unsigned short*)(outp3 + (size_t)16 * CIN_B * CIN_S); // 512*8192
    // total ws ~48 MB; cin_l3's <=64 B tail over-read on G stays in-ws? G is
    // the LAST buffer -- give it a 64 B pad by construction (8192-elem rows
    // end exactly at k=8192; the final prefetch reads row k-chunk end +64 B
    // which is the next row for all but the last row; last row's tail reads
    // the bytes after G: keep 1 KB slack after G in ws).

    // 1 merged prep dispatch (was 4): see prep_all ranges.
    prep_all<<<4992, 256, 0, stream>>>(X, W0, W1, W2, Wtk1, Wtk2, W2t, X0hd, Xh);

    // layer 1: NB=2, writes H1 + out[:,0:200] direct
    cin_layer<3, 3, 48, 1, 2, 4><<<dim3(CIN_B / 2, 1), 448, 0, stream>>>(
        X0hd, Xh, Wtk1, H1, out);
    // layer 2: NB=2 R0-proven structure; coalesced jh-partials
    cin_layer<7, 13, 224, 2, 2, 4><<<dim3(CIN_B / 2, 2), 448, 0, stream>>>(
        H1, Xh, Wtk2, Hacc, outp2);

    // fused combine + G outer-product
    cin_g<<<CIN_B, 448, 0, stream>>>(Xh, Hacc, G);
    // layer-3 GEMM -> 16 k-chunk partials
    cin_l3<<<dim3(7, 16, 16), 64, 0, stream>>>(W2t, G, outp3);

    cin_outc<<<(CIN_B * 400) / 256, 256, 0, stream>>>(outp2, outp3, out);
}